// Round 1
// baseline (49729.913 us; speedup 1.0000x reference)
//
#include <hip/hip_runtime.h>
#include <math.h>

#define B_   32
#define TE   1024
#define TD   512
#define E_   512
#define U_   512
#define F_   32
#define K_   31
#define KH   15   // (K_-1)/2

__device__ __forceinline__ float tanh_fast(float x) {
    // tanh(x) = (e^{2x}-1)/(e^{2x}+1), clamped so exp2 never overflows.
    x = fminf(10.0f, fmaxf(-10.0f, x));
    float t = __builtin_amdgcn_exp2f(x * 2.885390081777927f); // 2*log2(e)
    return (t - 1.0f) * __builtin_amdgcn_rcpf(t + 1.0f);
}

// ---------------------------------------------------------------------------
// Kernel A: energies e_raw[b,t] = sum_u v[u]*tanh(enc[b,t,u]+q[b,u]+loc[b,t,u]+ba[u])
// grid (TE/32, B), block 256 (4 waves). Each block: one b, 32 t, all 512 u.
// Thread (lane g, wave tg): t = t0+tg*8+i (i<8), u in {4g..4g+3} u {256+4g..256+4g+3}.
// w_loc staged in LDS in two 16-row halves (32 KB) to stay under 64 KB static LDS.
// ---------------------------------------------------------------------------
__global__ __launch_bounds__(256)
void energy_kernel(const float* __restrict__ enc,   // B,TE,E
                   const float* __restrict__ dec,   // B,TD,E
                   const float* __restrict__ cw,    // K,1,F
                   const float* __restrict__ cb,    // F
                   const float* __restrict__ wloc,  // F,U
                   const float* __restrict__ va,    // U
                   const float* __restrict__ ba,    // U
                   const float* __restrict__ pa,    // B,TE  (cumulated alignment)
                   float* __restrict__ eraw,        // B,TE
                   int step)
{
    __shared__ float Wh[16 * 512];          // 32 KB: half of w_loc
    __shared__ float fT[F_][32];            // conv features, [c][t_local]
    __shared__ float paS[32 + 2 * KH];      // 62-wide alignment window

    const int b   = blockIdx.y;
    const int t0  = blockIdx.x * 32;
    const int tid = threadIdx.x;
    const int g   = tid & 63;               // lane
    const int tg  = tid >> 6;               // wave 0..3

    // --- stage prev_align window [t0-15, t0+47) with zero padding ---
    if (tid < 62) {
        int t = t0 - KH + tid;
        paS[tid] = (t >= 0 && t < TE) ? pa[(size_t)b * TE + t] : 0.0f;
    }
    __syncthreads();

    // --- location conv: fT[c][t] = cb[c] + sum_k paS[t+k]*cw[k,c] ---
    {
        int c  = tid & 31;
        int ts = tid >> 5;                  // 0..7, each handles 4 t
        #pragma unroll
        for (int i = 0; i < 4; ++i) {
            int t = ts * 4 + i;
            float acc = cb[c];
            #pragma unroll
            for (int k = 0; k < K_; ++k)
                acc += paS[t + k] * cw[k * F_ + c];
            fT[c][t] = acc;
        }
    }

    // --- loc matmul, register-blocked 8t x 8u per thread ---
    float accv[8][8];
    #pragma unroll
    for (int i = 0; i < 8; ++i)
        #pragma unroll
        for (int j = 0; j < 8; ++j) accv[i][j] = 0.0f;

    #pragma unroll
    for (int p = 0; p < 2; ++p) {
        __syncthreads();                    // fT ready (p=0) / phase-0 reads done (p=1)
        {   // stage rows [16p, 16p+16) of w_loc
            const float4* wsrc = (const float4*)wloc;
            float4* wdst = (float4*)Wh;
            #pragma unroll
            for (int j = 0; j < 8; ++j)
                wdst[j * 256 + tid] = wsrc[p * 2048 + j * 256 + tid];
        }
        __syncthreads();
        #pragma unroll
        for (int c16 = 0; c16 < 16; ++c16) {
            int c = p * 16 + c16;
            float4 fa = *(const float4*)&fT[c][tg * 8];
            float4 fb = *(const float4*)&fT[c][tg * 8 + 4];
            float4 w0 = *(const float4*)&Wh[c16 * 512 + 4 * g];         // u = 4g..
            float4 w1 = *(const float4*)&Wh[c16 * 512 + 256 + 4 * g];   // u = 256+4g..
            float fv[8] = {fa.x, fa.y, fa.z, fa.w, fb.x, fb.y, fb.z, fb.w};
            #pragma unroll
            for (int i = 0; i < 8; ++i) {
                accv[i][0] += fv[i] * w0.x; accv[i][1] += fv[i] * w0.y;
                accv[i][2] += fv[i] * w0.z; accv[i][3] += fv[i] * w0.w;
                accv[i][4] += fv[i] * w1.x; accv[i][5] += fv[i] * w1.y;
                accv[i][6] += fv[i] * w1.z; accv[i][7] += fv[i] * w1.w;
            }
        }
    }

    // --- epilogue: + enc + query + ba, tanh, dot with va, wave-reduce over u ---
    const float4* q4 = (const float4*)(dec + ((size_t)b * TD + step) * E_);
    float4 qa = q4[g],  qb = q4[64 + g];
    float4 Ba = ((const float4*)ba)[g], Bb = ((const float4*)ba)[64 + g];
    float4 Va = ((const float4*)va)[g], Vb = ((const float4*)va)[64 + g];

    #pragma unroll
    for (int i = 0; i < 8; ++i) {
        int t = t0 + tg * 8 + i;
        const float4* e4 = (const float4*)(enc + ((size_t)b * TE + t) * E_);
        float4 ea = e4[g], eb = e4[64 + g];
        float s =
            Va.x * tanh_fast(accv[i][0] + ea.x + qa.x + Ba.x) +
            Va.y * tanh_fast(accv[i][1] + ea.y + qa.y + Ba.y) +
            Va.z * tanh_fast(accv[i][2] + ea.z + qa.z + Ba.z) +
            Va.w * tanh_fast(accv[i][3] + ea.w + qa.w + Ba.w) +
            Vb.x * tanh_fast(accv[i][4] + eb.x + qb.x + Bb.x) +
            Vb.y * tanh_fast(accv[i][5] + eb.y + qb.y + Bb.y) +
            Vb.z * tanh_fast(accv[i][6] + eb.z + qb.z + Bb.z) +
            Vb.w * tanh_fast(accv[i][7] + eb.w + qb.w + Bb.w);
        #pragma unroll
        for (int off = 32; off; off >>= 1) s += __shfl_xor(s, off);
        if (g == 0) eraw[(size_t)b * TE + t] = s;
    }
}

// ---------------------------------------------------------------------------
// Kernel B: row softmax over t, write e to output, cumulate into prev_align.
// grid B_, block 256 (4 floats/thread).
// ---------------------------------------------------------------------------
__global__ __launch_bounds__(256)
void softmax_kernel(const float* __restrict__ eraw,  // B,TE
                    float* __restrict__ pa,          // B,TE
                    float* __restrict__ eout,        // B,TD,TE
                    int step)
{
    __shared__ float redm[4], reds[4];
    const int b = blockIdx.x, tid = threadIdx.x;
    const int lane = tid & 63, w = tid >> 6;

    const float4* er4 = (const float4*)(eraw + (size_t)b * TE);
    float4 v = er4[tid];
    float m = fmaxf(fmaxf(v.x, v.y), fmaxf(v.z, v.w));
    #pragma unroll
    for (int off = 32; off; off >>= 1) m = fmaxf(m, __shfl_xor(m, off));
    if (lane == 0) redm[w] = m;
    __syncthreads();
    m = fmaxf(fmaxf(redm[0], redm[1]), fmaxf(redm[2], redm[3]));

    const float L2E = 1.4426950408889634f;
    float4 p;
    p.x = __builtin_amdgcn_exp2f((v.x - m) * L2E);
    p.y = __builtin_amdgcn_exp2f((v.y - m) * L2E);
    p.z = __builtin_amdgcn_exp2f((v.z - m) * L2E);
    p.w = __builtin_amdgcn_exp2f((v.w - m) * L2E);
    float s = p.x + p.y + p.z + p.w;
    #pragma unroll
    for (int off = 32; off; off >>= 1) s += __shfl_xor(s, off);
    if (lane == 0) reds[w] = s;
    __syncthreads();
    float tot = reds[0] + reds[1] + reds[2] + reds[3];
    float inv = 1.0f / tot;
    p.x *= inv; p.y *= inv; p.z *= inv; p.w *= inv;

    *(float4*)&eout[((size_t)b * TD + step) * TE + tid * 4] = p;

    float4* pa4 = (float4*)(pa + (size_t)b * TE);
    float4 pv = pa4[tid];
    pv.x += p.x; pv.y += p.y; pv.z += p.z; pv.w += p.w;
    pa4[tid] = pv;
}

// ---------------------------------------------------------------------------
// Kernel C: c[b,d,e] = sum_t eo[b,d,t] * enc[b,t,e]
// grid (TD/32, B), block 256. Thread owns e-pair 2*tid, 32 d accumulators.
// ---------------------------------------------------------------------------
__global__ __launch_bounds__(256)
void context_kernel(const float* __restrict__ eo,   // B,TD,TE
                    const float* __restrict__ enc,  // B,TE,E
                    float* __restrict__ cout)       // B,TD,E
{
    __shared__ float eoT[64][36];                  // [t][d], padded stride 36
    const int b = blockIdx.y, d0 = blockIdx.x * 32, tid = threadIdx.x;

    float2 acc[32];
    #pragma unroll
    for (int d = 0; d < 32; ++d) { acc[d].x = 0.0f; acc[d].y = 0.0f; }

    for (int tc = 0; tc < TE / 64; ++tc) {
        __syncthreads();
        #pragma unroll
        for (int r = 0; r < 8; ++r) {
            int lin = r * 256 + tid;
            int d = lin >> 6, t = lin & 63;
            eoT[t][d] = eo[((size_t)b * TD + d0 + d) * TE + tc * 64 + t];
        }
        __syncthreads();
        #pragma unroll 4
        for (int t = 0; t < 64; ++t) {
            float2 ev = *(const float2*)&enc[((size_t)b * TE + tc * 64 + t) * E_ + 2 * tid];
            #pragma unroll
            for (int dq = 0; dq < 8; ++dq) {
                float4 w = *(const float4*)&eoT[t][dq * 4];
                acc[dq * 4 + 0].x += w.x * ev.x; acc[dq * 4 + 0].y += w.x * ev.y;
                acc[dq * 4 + 1].x += w.y * ev.x; acc[dq * 4 + 1].y += w.y * ev.y;
                acc[dq * 4 + 2].x += w.z * ev.x; acc[dq * 4 + 2].y += w.z * ev.y;
                acc[dq * 4 + 3].x += w.w * ev.x; acc[dq * 4 + 3].y += w.w * ev.y;
            }
        }
    }
    #pragma unroll
    for (int d = 0; d < 32; ++d)
        *(float2*)&cout[((size_t)b * TD + d0 + d) * E_ + 2 * tid] = acc[d];
}

// ---------------------------------------------------------------------------
extern "C" void kernel_launch(void* const* d_in, const int* in_sizes, int n_in,
                              void* d_out, int out_size, void* d_ws, size_t ws_size,
                              hipStream_t stream) {
    const float* enc  = (const float*)d_in[0];
    const float* dec  = (const float*)d_in[1];
    const float* cw   = (const float*)d_in[2];
    const float* cb   = (const float*)d_in[3];
    const float* wloc = (const float*)d_in[4];
    const float* va   = (const float*)d_in[5];
    const float* ba   = (const float*)d_in[6];

    float* c_out = (float*)d_out;                          // B*TD*E
    float* e_out = (float*)d_out + (size_t)B_ * TD * E_;   // B*TD*TE

    float* pa   = (float*)d_ws;                            // B*TE
    float* eraw = pa + (size_t)B_ * TE;                    // B*TE

    hipMemsetAsync(pa, 0, (size_t)B_ * TE * sizeof(float), stream);

    dim3 gA(TE / 32, B_);
    for (int s = 0; s < TD; ++s) {
        energy_kernel<<<gA, 256, 0, stream>>>(enc, dec, cw, cb, wloc, va, ba,
                                              pa, eraw, s);
        softmax_kernel<<<B_, 256, 0, stream>>>(eraw, pa, e_out, s);
    }
    context_kernel<<<dim3(TD / 32, B_), 256, 0, stream>>>(e_out, enc, c_out);
}